// Round 16
// baseline (1305.250 us; speedup 1.0000x reference)
//
#include <hip/hip_runtime.h>
#include <hip/hip_fp16.h>
#include <cmath>

#define Wd 256
#define Hd 256
#define HWd 65536
#define NTOT 4194304
#define NACC 51
#define NSLOT 64                     // atomic slots per step, one 64B line each

#define C_COUP (2.0f / 4194304.0f)   // 2*COUPLING/N
#define C_KIN  (0.2f / 4194304.0f)   // 2*ALPHA/N
#define C_VOID 0.0098f               // 2*GAMMA^2
#define SCFP 68719476736.0           // 2^36 fixed-point scale

typedef unsigned int u32x4 __attribute__((ext_vector_type(4)));

// non-temporal 16B load/store via clang native vector (HIP_vector_type not accepted)
__device__ __forceinline__ uint4 ntload4(const unsigned* p) {
    u32x4 v = __builtin_nontemporal_load((const u32x4*)p);
    return make_uint4(v.x, v.y, v.z, v.w);
}
__device__ __forceinline__ void ntstore4(unsigned* p, unsigned a, unsigned b,
                                         unsigned c, unsigned d) {
    u32x4 v = {a, b, c, d};
    __builtin_nontemporal_store(v, (u32x4*)p);
}

// ---- packed bf16 pair helpers for Adam state ----
__device__ __forceinline__ float bflo(unsigned w) { return __uint_as_float(w << 16); }
__device__ __forceinline__ float bfhi(unsigned w) { return __uint_as_float(w & 0xFFFF0000u); }
// hardware pack: lo=bf16(a), hi=bf16(b), RNE (deterministic)
__device__ __forceinline__ unsigned bfpack(float a, float b) {
    unsigned r;
    asm volatile("v_cvt_pk_bf16_f32 %0, %1, %2" : "=v"(r) : "v"(a), "v"(b));
    return r;
}

// ---- packed fp16 pair helpers (deterministic) ----
__device__ __forceinline__ unsigned packh2(float a, float b) {
    __half2 h = __floats2half2_rn(a, b);
    return *(unsigned*)&h;
}
// hardware pack RTZ (1 instr) for the phi ping-pong
__device__ __forceinline__ unsigned packh2z(float a, float b) {
    auto h = __builtin_amdgcn_cvt_pkrtz(a, b);
    return *(unsigned*)&h;
}
__device__ __forceinline__ __half2 ash2(unsigned w) { return *(__half2*)&w; }
__device__ __forceinline__ unsigned asu32(__half2 h) { return *(unsigned*)&h; }

// block-level reduce of phi^2 sums -> one deterministic fixed-point atomic pair
__device__ __forceinline__ void block_acc(float sumx, float sumy, float* sRed,
                                          unsigned long long* slot) {
    for (int off = 32; off > 0; off >>= 1) {
        sumx += __shfl_down(sumx, off, 64);
        sumy += __shfl_down(sumy, off, 64);
    }
    const int tid = threadIdx.x;
    const int wid = tid >> 6;
    if ((tid & 63) == 0) { sRed[wid] = sumx; sRed[4 + wid] = sumy; }
    __syncthreads();
    if (tid == 0) {
        float fx = sRed[0] + sRed[1] + sRed[2] + sRed[3];
        float fy = sRed[4] + sRed[5] + sRed[6] + sRed[7];
        atomicAdd(&slot[0], (unsigned long long)((double)fx * SCFP + 0.5));
        atomicAdd(&slot[1], (unsigned long long)((double)fy * SCFP + 0.5));
    }
}

// mode: 0 = write packed only; 1 = packed + f32 outs (step 49);
//       2 = f32 outs + sp, no packed/state (step 50). first: t==1 (m,v implicit zero)
__global__ __launch_bounds__(256, 8)
void k_step(const float* __restrict__ S,
            const unsigned* __restrict__ dxy,
            const unsigned* __restrict__ pPrev, unsigned* __restrict__ pCur,
            unsigned* __restrict__ mP, unsigned* __restrict__ vP,
            const unsigned long long* __restrict__ accPrev,
            unsigned long long* __restrict__ accCur,
            float a2, int mode, int first,
            float* __restrict__ outx, float* __restrict__ outy,
            float* __restrict__ sp)
{
    __shared__ __align__(16) unsigned sP[36][40];    // phi strip packed half2
    __shared__ __align__(16) unsigned sA[36][40];    // interior: row-pass D; border: c1
    __shared__ __align__(16) unsigned sB[36][40];    // interior: row-pass S; border: c2
    __shared__ float sRed[8];

    const int tid = threadIdx.x;
    const int cgi = tid & 7;
    const int rr  = tid >> 3;
    // XCD-aware bijective swizzle (4096 % 8 == 0): each XCD owns 8 full z-slices
    const int swz = ((blockIdx.x & 7) << 9) | (blockIdx.x >> 3);
    const int bx  = swz & 7;
    const int by  = (swz >> 3) & 7;
    const int zsl = swz >> 6;
    const int x0  = bx * 32;
    const int y0  = by * 32;
    const size_t base = (size_t)zsl * HWd;
    const int gy = y0 + rr;
    const int gxb = x0 + 4 * cgi;
    const size_t idx = base + (size_t)gy * Wd + gxb;
    const bool interior = (bx != 0) & (bx != 7) & (by != 0) & (by != 7);
    // composed 5x5 path produces dK*64 -> fold /64 into the kinetic constant
    const float ckin = interior ? (C_KIN * 0.015625f) : C_KIN;

    // ---- hoisted global loads: latency hides under the LDS phases ----
    // m,v and dxy are streamed (no L2 reuse possible: 8MB/XCD) -> non-temporal,
    // keeps L2 free for the phi ping-pong (2MB/XCD, reused across steps)
    uint4 d4 = ntload4(dxy + idx);
    uint4 mp4 = make_uint4(0u, 0u, 0u, 0u), vp4 = make_uint4(0u, 0u, 0u, 0u);
    if (!first) {
        mp4 = ntload4(mP + idx);
        vp4 = ntload4(vP + idx);
    }
    float4 s4 = make_float4(0.f, 0.f, 0.f, 0.f);
    if (mode == 2) s4 = *(const float4*)(S + idx);

    // ---- strip load: 360 uint4 tasks, stored packed ----
    if (interior) {
#pragma unroll
        for (int k = 0; k < 2; ++k) {
            int task = tid + (k << 8);
            if (task < 360) {
                int u = (task * 205) >> 11;      // task/10 exact for task<360
                int v = task - 10 * u;
                *(uint4*)&sP[u][4 * v] =
                    *(const uint4*)(pPrev + base + (size_t)(y0 - 2 + u) * Wd + (x0 - 4 + 4 * v));
            }
        }
    } else {
#pragma unroll
        for (int k = 0; k < 2; ++k) {
            int task = tid + (k << 8);
            if (task < 360) {
                int u = (task * 205) >> 11;
                int v = task - 10 * u;
                int gyy = y0 - 2 + u, gxx = x0 - 4 + 4 * v;
                uint4 w = make_uint4(0u, 0u, 0u, 0u);
                if ((unsigned)gyy < 256u && (unsigned)gxx < 256u)
                    w = *(const uint4*)(pPrev + base + (size_t)gyy * Wd + gxx);
                *(uint4*)&sP[u][4 * v] = w;
            }
        }
    }

    // ---- SSB coef prologue on wave 3 only (overlaps strip load) ----
    if (tid >= 192) {
        int l = tid - 192;
        unsigned long long ax = accPrev[l * 8];
        unsigned long long ay = accPrev[l * 8 + 1];
#pragma unroll
        for (int off = 1; off < 64; off <<= 1) {
            ax += __shfl_xor(ax, off, 64);
            ay += __shfl_xor(ay, off, 64);
        }
        if (l == 0) {
            double axd = (double)ax * (1.0 / SCFP);
            double ayd = (double)ay * (1.0 / SCFP);
            double nxd = sqrt(axd), nyd = sqrt(ayd);
            double pnd = nxd + nyd;
            double uu = pnd * pnd - 0.01;             // V^2
            double sg = (uu > 0.0) ? 1.0 : ((uu < 0.0) ? -1.0 : 0.0);
            sRed[6] = (float)(0.2 * sg * pnd / nxd);
            sRed[7] = (float)(0.2 * sg * pnd / nyd);
        }
    }
    __syncthreads();
    const float coefx = sRed[6];
    const float coefy = sRed[7];

    const __half2 k8 = __float2half2_rn(0.125f);
    const __half2 k4 = __float2half2_rn(0.25f);
    const __half2 h4 = __float2half2_rn(4.0f);
    const __half2 h6 = __float2half2_rn(6.0f);
    const __half2 hn2 = __float2half2_rn(-2.0f);

    float dKx[4], dKy[4], pxa[4], pya[4];

    if (interior) {
        // ---- row pass: 288 tasks (36 rows x 8 groups), composed-kernel halves
        //  A = phi[x-2] - 2 phi[x] + phi[x+2]   (D row)
        //  B = phi[x-2] + 4 phi[x-1] + 6 phi[x] + 4 phi[x+1] + phi[x+2]  (S row)
#pragma unroll
        for (int k = 0; k < 2; ++k) {
            int task = tid + (k << 8);
            if (task < 288) {
                int u = task >> 3, g = task & 7;
                uint4 W0 = *(uint4*)&sP[u][4 * g];
                uint4 W1 = *(uint4*)&sP[u][4 * g + 4];
                uint4 W2 = *(uint4*)&sP[u][4 * g + 8];
                __half2 w[12] = {ash2(W0.x), ash2(W0.y), ash2(W0.z), ash2(W0.w),
                                 ash2(W1.x), ash2(W1.y), ash2(W1.z), ash2(W1.w),
                                 ash2(W2.x), ash2(W2.y), ash2(W2.z), ash2(W2.w)};
                unsigned au[4], bu[4];
#pragma unroll
                for (int jj = 0; jj < 4; ++jj) {
                    __half2 e = __hadd2(w[2 + jj], w[6 + jj]);
                    __half2 A = __hfma2(hn2, w[4 + jj], e);
                    __half2 f = __hadd2(w[3 + jj], w[5 + jj]);
                    __half2 B = __hfma2(h6, w[4 + jj], __hfma2(h4, f, e));
                    au[jj] = asu32(A);
                    bu[jj] = asu32(B);
                }
                *(uint4*)&sA[u][4 * g] = make_uint4(au[0], au[1], au[2], au[3]);
                *(uint4*)&sB[u][4 * g] = make_uint4(bu[0], bu[1], bu[2], bu[3]);
            }
        }
        __syncthreads();

        // ---- column pass: dK_raw = S-col(A) + D-col(B) (scale folded in ckin)
        {
            uint4 pw = *(uint4*)&sP[rr + 2][4 * cgi + 4];
            unsigned pwv[4] = {pw.x, pw.y, pw.z, pw.w};
#pragma unroll
            for (int j = 0; j < 4; ++j) {
                float2 f = __half22float2(ash2(pwv[j]));
                pxa[j] = f.x; pya[j] = f.y;
            }
            const int cb = 4 * cgi;
            uint4 A0 = *(uint4*)&sA[rr][cb];
            uint4 A1 = *(uint4*)&sA[rr + 1][cb];
            uint4 A2 = *(uint4*)&sA[rr + 2][cb];
            uint4 A3 = *(uint4*)&sA[rr + 3][cb];
            uint4 A4 = *(uint4*)&sA[rr + 4][cb];
            uint4 B0 = *(uint4*)&sB[rr][cb];
            uint4 B2 = *(uint4*)&sB[rr + 2][cb];
            uint4 B4 = *(uint4*)&sB[rr + 4][cb];
            unsigned a0[4] = {A0.x, A0.y, A0.z, A0.w};
            unsigned a1[4] = {A1.x, A1.y, A1.z, A1.w};
            unsigned a2v[4] = {A2.x, A2.y, A2.z, A2.w};
            unsigned a3[4] = {A3.x, A3.y, A3.z, A3.w};
            unsigned a4[4] = {A4.x, A4.y, A4.z, A4.w};
            unsigned b0[4] = {B0.x, B0.y, B0.z, B0.w};
            unsigned b2[4] = {B2.x, B2.y, B2.z, B2.w};
            unsigned b4[4] = {B4.x, B4.y, B4.z, B4.w};
#pragma unroll
            for (int jj = 0; jj < 4; ++jj) {
                __half2 g1 = __hadd2(ash2(a0[jj]), ash2(a4[jj]));
                __half2 g2 = __hadd2(ash2(a1[jj]), ash2(a3[jj]));
                __half2 colA = __hfma2(h6, ash2(a2v[jj]), __hfma2(h4, g2, g1));
                __half2 g3 = __hadd2(ash2(b0[jj]), ash2(b4[jj]));
                __half2 colB = __hfma2(hn2, ash2(b2[jj]), g3);
                float2 f = __half22float2(__hadd2(colA, colB));
                dKx[jj] = f.x; dKy[jj] = f.y;
            }
        }
    } else {
        // ---- border: exact two-stage path (c-stage then d-stage) ----
#pragma unroll
        for (int k = 0; k < 2; ++k) {
            int task = tid + (k << 8);
            if (task < 306) {
                int a = (task * 57) >> 9;            // task/9 exact for task<306
                int v = task - 9 * a;
                uint4 T0 = *(uint4*)&sP[a][4 * v];     uint4 T1 = *(uint4*)&sP[a][4 * v + 4];
                uint4 M0 = *(uint4*)&sP[a + 1][4 * v]; uint4 M1 = *(uint4*)&sP[a + 1][4 * v + 4];
                uint4 B0 = *(uint4*)&sP[a + 2][4 * v]; uint4 B1 = *(uint4*)&sP[a + 2][4 * v + 4];
                __half2 wt[6] = {ash2(T0.x), ash2(T0.y), ash2(T0.z), ash2(T0.w), ash2(T1.x), ash2(T1.y)};
                __half2 wm[6] = {ash2(M0.x), ash2(M0.y), ash2(M0.z), ash2(M0.w), ash2(M1.x), ash2(M1.y)};
                __half2 wb[6] = {ash2(B0.x), ash2(B0.y), ash2(B0.z), ash2(B0.w), ash2(B1.x), ash2(B1.y)};
                int gyy = y0 - 1 + a;
                bool rowok = (unsigned)gyy < 256u;
                unsigned c1u[4], c2u[4];
#pragma unroll
                for (int jj = 0; jj < 4; ++jj) {
                    __half2 c1 = __hfma2(k4, __hsub2(wm[jj + 2], wm[jj]),
                                 __hmul2(k8, __hadd2(__hsub2(wt[jj + 2], wt[jj]),
                                                     __hsub2(wb[jj + 2], wb[jj]))));
                    __half2 c2 = __hfma2(k4, __hsub2(wb[jj + 1], wt[jj + 1]),
                                 __hmul2(k8, __hadd2(__hsub2(wb[jj], wt[jj]),
                                                     __hsub2(wb[jj + 2], wt[jj + 2]))));
                    unsigned msk = (rowok && (unsigned)(x0 + 4 * v - 3 + jj) < 256u)
                                   ? 0xFFFFFFFFu : 0u;
                    c1u[jj] = asu32(c1) & msk;
                    c2u[jj] = asu32(c2) & msk;
                }
                *(uint4*)&sA[a][4 * v] = make_uint4(c1u[0], c1u[1], c1u[2], c1u[3]);
                *(uint4*)&sB[a][4 * v] = make_uint4(c2u[0], c2u[1], c2u[2], c2u[3]);
            }
        }
        __syncthreads();
        {
            uint4 pw = *(uint4*)&sP[rr + 2][4 * cgi + 4];
            unsigned pwv[4] = {pw.x, pw.y, pw.z, pw.w};
#pragma unroll
            for (int j = 0; j < 4; ++j) {
                float2 f = __half22float2(ash2(pwv[j]));
                pxa[j] = f.x; pya[j] = f.y;
            }
            const int cb = 4 * cgi;
            uint4 U0a = *(uint4*)&sA[rr][cb];     uint4 U0b = *(uint4*)&sA[rr][cb + 4];
            uint4 U1a = *(uint4*)&sA[rr + 1][cb]; uint4 U1b = *(uint4*)&sA[rr + 1][cb + 4];
            uint4 U2a = *(uint4*)&sA[rr + 2][cb]; uint4 U2b = *(uint4*)&sA[rr + 2][cb + 4];
            uint4 V0a = *(uint4*)&sB[rr][cb];     uint4 V0b = *(uint4*)&sB[rr][cb + 4];
            uint4 V2a = *(uint4*)&sB[rr + 2][cb]; uint4 V2b = *(uint4*)&sB[rr + 2][cb + 4];
            __half2 u0[8] = {ash2(U0a.x), ash2(U0a.y), ash2(U0a.z), ash2(U0a.w),
                             ash2(U0b.x), ash2(U0b.y), ash2(U0b.z), ash2(U0b.w)};
            __half2 u1[8] = {ash2(U1a.x), ash2(U1a.y), ash2(U1a.z), ash2(U1a.w),
                             ash2(U1b.x), ash2(U1b.y), ash2(U1b.z), ash2(U1b.w)};
            __half2 u2[8] = {ash2(U2a.x), ash2(U2a.y), ash2(U2a.z), ash2(U2a.w),
                             ash2(U2b.x), ash2(U2b.y), ash2(U2b.z), ash2(U2b.w)};
            __half2 t0[8] = {ash2(V0a.x), ash2(V0a.y), ash2(V0a.z), ash2(V0a.w),
                             ash2(V0b.x), ash2(V0b.y), ash2(V0b.z), ash2(V0b.w)};
            __half2 t2[8] = {ash2(V2a.x), ash2(V2a.y), ash2(V2a.z), ash2(V2a.w),
                             ash2(V2b.x), ash2(V2b.y), ash2(V2b.z), ash2(V2b.w)};
#pragma unroll
            for (int jj = 0; jj < 4; ++jj) {
                __half2 A = __hadd2(__hadd2(__hsub2(u0[jj + 4], u0[jj + 2]),
                                            __hsub2(u2[jj + 4], u2[jj + 2])),
                                    __hadd2(__hsub2(t2[jj + 2], t0[jj + 2]),
                                            __hsub2(t2[jj + 4], t0[jj + 4])));
                __half2 B = __hadd2(__hsub2(u1[jj + 4], u1[jj + 2]),
                                    __hsub2(t2[jj + 3], t0[jj + 3]));
                __half2 dk = __hfma2(k4, B, __hmul2(k8, A));
                float2 f = __half22float2(dk);
                dKx[jj] = f.x; dKy[jj] = f.y;
            }
        }
    }

    // ---- pointwise grad + Adam (dx,dy,void precomputed; rsqrt update) ----
    unsigned duv[4] = {d4.x, d4.y, d4.z, d4.w};
    unsigned mpv[4] = {mp4.x, mp4.y, mp4.z, mp4.w};
    unsigned vpv[4] = {vp4.x, vp4.y, vp4.z, vp4.w};
    float sa[4] = {s4.x, s4.y, s4.z, s4.w};

    unsigned nmw[4], nvw[4], npk[4];
    float npx[4], npy[4], spv[4];
    float sumx = 0.f, sumy = 0.f;
#pragma unroll
    for (int j = 0; j < 4; ++j) {
        float2 dd = __half22float2(ash2(duv[j]));
        float dx_ = dd.x, dy_ = dd.y;
        float vmc = (duv[j] & 1u) ? C_VOID : 0.f;
        float R = pxa[j] * dx_ + pya[j] * dy_;
        float gx_ = C_COUP * R * dx_ - ckin * dKx[j] + (coefx + vmc) * pxa[j];
        float gy_ = C_COUP * R * dy_ - ckin * dKy[j] + (coefy + vmc) * pya[j];

        float m1 = first ? (0.1f * gx_) : (0.9f * bflo(mpv[j]) + 0.1f * gx_);
        float v1 = first ? (0.001f * gx_ * gx_) : (0.999f * bflo(vpv[j]) + 0.001f * gx_ * gx_);
        npx[j] = fmaf(-a2 * m1, __frsqrt_rn(v1), pxa[j]);
        sumx += npx[j] * npx[j];

        float m2 = first ? (0.1f * gy_) : (0.9f * bfhi(mpv[j]) + 0.1f * gy_);
        float v2 = first ? (0.001f * gy_ * gy_) : (0.999f * bfhi(vpv[j]) + 0.001f * gy_ * gy_);
        npy[j] = fmaf(-a2 * m2, __frsqrt_rn(v2), pya[j]);
        sumy += npy[j] * npy[j];

        nmw[j] = bfpack(m1, m2);
        nvw[j] = bfpack(v1, v2);
        npk[j] = packh2z(npx[j], npy[j]);
        spv[j] = sa[j] + R;
    }
    if (mode != 2) {   // last step: state never read again
        ntstore4(mP + idx, nmw[0], nmw[1], nmw[2], nmw[3]);
        ntstore4(vP + idx, nvw[0], nvw[1], nvw[2], nvw[3]);
        *(uint4*)(pCur + idx) = make_uint4(npk[0], npk[1], npk[2], npk[3]);
    }
    if (mode != 0) {
        *(float4*)(outx + idx) = make_float4(npx[0], npx[1], npx[2], npx[3]);
        *(float4*)(outy + idx) = make_float4(npy[0], npy[1], npy[2], npy[3]);
    }
    if (mode == 2) {
        *(float4*)(sp + idx) = make_float4(spv[0], spv[1], spv[2], spv[3]);
        return;   // acc[50] is never read — skip the reduce+atomic
    }

    block_acc(sumx, sumy, sRed, accCur + (size_t)zsl * 8);
}

// init: pack phi0 -> p0, precompute packed (dx,dy,void) from S, ||phi0||^2
__global__ __launch_bounds__(256)
void k_init(const float* __restrict__ S,
            const float* __restrict__ px0, const float* __restrict__ py0,
            unsigned* __restrict__ p0, unsigned* __restrict__ dxy,
            unsigned long long* __restrict__ acc0)
{
    __shared__ float sRed[8];
    const int tid = threadIdx.x;
    float sx = 0.f, sy = 0.f;
#pragma unroll
    for (int k = 0; k < 2; ++k) {
        size_t idx = (size_t)blockIdx.x * 2048 + (size_t)(k * 1024 + tid * 4);
        float4 x = *(const float4*)(px0 + idx);
        float4 y = *(const float4*)(py0 + idx);
        *(uint4*)(p0 + idx) = make_uint4(packh2(x.x, y.x), packh2(x.y, y.y),
                                         packh2(x.z, y.z), packh2(x.w, y.w));
        sx += x.x * x.x + x.y * x.y + x.z * x.z + x.w * x.w;
        sy += y.x * y.x + y.y * y.y + y.z * y.z + y.w * y.w;

        // dx,dy,void pack
        int col = (int)(idx & 255u);
        int row = (int)((idx >> 8) & 255u);
        float4 s4 = *(const float4*)(S + idx);
        float sa[4] = {s4.x, s4.y, s4.z, s4.w};
        float sE = (col + 4 < 256) ? S[idx + 4] : 0.f;
        float4 sD = (row < 255) ? *(const float4*)(S + idx + 256) : make_float4(0.f, 0.f, 0.f, 0.f);
        float sd[4] = {sD.x, sD.y, sD.z, sD.w};
        unsigned du[4];
#pragma unroll
        for (int j = 0; j < 4; ++j) {
            float dx_ = (j < 3) ? (sa[j + 1] - sa[j]) : ((col + 4 < 256) ? (sE - sa[3]) : 0.f);
            float dy_ = (row < 255) ? (sd[j] - sa[j]) : 0.f;
            unsigned u = packh2(dx_, dy_);
            du[j] = (u & ~1u) | ((sa[j] < 0.05f) ? 1u : 0u);
        }
        *(uint4*)(dxy + idx) = make_uint4(du[0], du[1], du[2], du[3]);
    }
    block_acc(sx, sy, sRed, acc0 + (size_t)(blockIdx.x & (NSLOT - 1)) * 8);
}

extern "C" void kernel_launch(void* const* d_in, const int* in_sizes, int n_in,
                              void* d_out, int out_size, void* d_ws, size_t ws_size,
                              hipStream_t stream) {
    (void)in_sizes; (void)n_in; (void)out_size; (void)ws_size;
    const float* S   = (const float*)d_in[0];
    const float* px0 = (const float*)d_in[1];
    const float* py0 = (const float*)d_in[2];
    float* out = (float*)d_out;

    float* sp     = out;                      // slot 0: Sp
    float* outA_x = out + (size_t)NTOT;       // slot 1: phi_x post
    float* outA_y = out + 2 * (size_t)NTOT;   // slot 2: phi_y post
    float* outB_x = out + 3 * (size_t)NTOT;   // slot 3: phi_x pre
    float* outB_y = out + 4 * (size_t)NTOT;   // slot 4: phi_y pre

    unsigned* ws = (unsigned*)d_ws;
    unsigned* p0 = ws;                        // packed (fp16 phix, fp16 phiy), 16 MB
    unsigned* p1 = p0 + (size_t)NTOT;         // ping-pong partner, 16 MB
    unsigned* mP = p1 + (size_t)NTOT;         // packed (bf16 mx, bf16 my), 16 MB
    unsigned* vP = mP + (size_t)NTOT;         // packed (bf16 vx, bf16 vy), 16 MB
    unsigned* dxy = vP + (size_t)NTOT;        // packed (fp16 dx, fp16 dy | void), 16 MB
    unsigned long long* acc = (unsigned long long*)(dxy + (size_t)NTOT);  // [NACC][NSLOT][8]

    hipError_t e = hipMemsetAsync(acc, 0, (size_t)NACC * NSLOT * 8 * sizeof(unsigned long long), stream);
    (void)e;

    k_init<<<2048, 256, 0, stream>>>(S, px0, py0, p0, dxy, acc);

    for (int t = 1; t <= 50; ++t) {
        double bc1 = 1.0 - pow(0.9, (double)t);
        double bc2 = 1.0 - pow(0.999, (double)t);
        float a2 = (float)(0.05 / bc1 * sqrt(bc2));   // LR/bc1 * sqrt(bc2)
        bool odd = (t & 1) != 0;
        const unsigned* pPrev = odd ? p0 : p1;
        unsigned* pCur = odd ? p1 : p0;
        int mode = (t == 49) ? 1 : ((t == 50) ? 2 : 0);
        float* ox = (t == 50) ? outA_x : outB_x;   // mode1 -> pre slots, mode2 -> post
        float* oy = (t == 50) ? outA_y : outB_y;
        k_step<<<4096, 256, 0, stream>>>(S, dxy, pPrev, pCur, mP, vP,
                                         acc + (size_t)(t - 1) * NSLOT * 8,
                                         acc + (size_t)t * NSLOT * 8,
                                         a2, mode, (t == 1) ? 1 : 0,
                                         ox, oy, sp);
    }
}

// Round 17
// 1238.934 us; speedup vs baseline: 1.0535x; 1.0535x over previous
//
#include <hip/hip_runtime.h>
#include <hip/hip_fp16.h>
#include <cmath>

#define Wd 256
#define Hd 256
#define HWd 65536
#define NTOT 4194304
#define NACC 51
#define NSLOT 64                     // atomic slots per step, one 64B line each

#define C_COUP (2.0f / 4194304.0f)   // 2*COUPLING/N
#define C_KIN  (0.2f / 4194304.0f)   // 2*ALPHA/N
#define C_VOID 0.0098f               // 2*GAMMA^2
#define SCFP 68719476736.0           // 2^36 fixed-point scale

// ---- packed bf16 pair helpers for Adam state ----
__device__ __forceinline__ float bflo(unsigned w) { return __uint_as_float(w << 16); }
__device__ __forceinline__ float bfhi(unsigned w) { return __uint_as_float(w & 0xFFFF0000u); }
// hardware pack: lo=bf16(a), hi=bf16(b), RNE (deterministic)
__device__ __forceinline__ unsigned bfpack(float a, float b) {
    unsigned r;
    asm volatile("v_cvt_pk_bf16_f32 %0, %1, %2" : "=v"(r) : "v"(a), "v"(b));
    return r;
}

// ---- packed fp16 pair helpers (deterministic) ----
__device__ __forceinline__ unsigned packh2(float a, float b) {
    __half2 h = __floats2half2_rn(a, b);
    return *(unsigned*)&h;
}
// hardware pack RTZ (1 instr) for the phi ping-pong
__device__ __forceinline__ unsigned packh2z(float a, float b) {
    auto h = __builtin_amdgcn_cvt_pkrtz(a, b);
    return *(unsigned*)&h;
}
__device__ __forceinline__ __half2 ash2(unsigned w) { return *(__half2*)&w; }
__device__ __forceinline__ unsigned asu32(__half2 h) { return *(unsigned*)&h; }

// block-level reduce of phi^2 sums -> one deterministic fixed-point atomic pair
__device__ __forceinline__ void block_acc(float sumx, float sumy, float* sRed,
                                          unsigned long long* slot) {
    for (int off = 32; off > 0; off >>= 1) {
        sumx += __shfl_down(sumx, off, 64);
        sumy += __shfl_down(sumy, off, 64);
    }
    const int tid = threadIdx.x;
    const int wid = tid >> 6;
    if ((tid & 63) == 0) { sRed[wid] = sumx; sRed[4 + wid] = sumy; }
    __syncthreads();
    if (tid == 0) {
        float fx = sRed[0] + sRed[1] + sRed[2] + sRed[3];
        float fy = sRed[4] + sRed[5] + sRed[6] + sRed[7];
        atomicAdd(&slot[0], (unsigned long long)((double)fx * SCFP + 0.5));
        atomicAdd(&slot[1], (unsigned long long)((double)fy * SCFP + 0.5));
    }
}

// mode: 0 = write packed only; 1 = packed + f32 outs (step 49);
//       2 = f32 outs + sp, no packed/state (step 50). first: t==1 (m,v implicit zero)
__global__ __launch_bounds__(256, 8)
void k_step(const float* __restrict__ S,
            const unsigned* __restrict__ dxy,
            const unsigned* __restrict__ pPrev, unsigned* __restrict__ pCur,
            unsigned* __restrict__ mP, unsigned* __restrict__ vP,
            const unsigned long long* __restrict__ accPrev,
            unsigned long long* __restrict__ accCur,
            float a2, int mode, int first,
            float* __restrict__ outx, float* __restrict__ outy,
            float* __restrict__ sp)
{
    __shared__ __align__(16) unsigned sP[36][40];    // phi strip packed half2
    __shared__ __align__(16) unsigned sA[36][40];    // interior: row-pass D; border: c1
    __shared__ __align__(16) unsigned sB[36][40];    // interior: row-pass S; border: c2
    __shared__ float sRed[8];

    const int tid = threadIdx.x;
    const int cgi = tid & 7;
    const int rr  = tid >> 3;
    // XCD-aware bijective swizzle (4096 % 8 == 0): each XCD owns 8 full z-slices
    const int swz = ((blockIdx.x & 7) << 9) | (blockIdx.x >> 3);
    const int bx  = swz & 7;
    const int by  = (swz >> 3) & 7;
    const int zsl = swz >> 6;
    const int x0  = bx * 32;
    const int y0  = by * 32;
    const size_t base = (size_t)zsl * HWd;
    const int gy = y0 + rr;
    const int gxb = x0 + 4 * cgi;
    const size_t idx = base + (size_t)gy * Wd + gxb;
    const bool interior = (bx != 0) & (bx != 7) & (by != 0) & (by != 7);
    // composed 5x5 path produces dK*64 -> fold /64 into the kinetic constant
    const float ckin = interior ? (C_KIN * 0.015625f) : C_KIN;

    // ---- hoisted global loads: latency hides under the LDS phases ----
    uint4 d4 = *(const uint4*)(dxy + idx);
    uint4 mp4 = make_uint4(0u, 0u, 0u, 0u), vp4 = make_uint4(0u, 0u, 0u, 0u);
    if (!first) { mp4 = *(const uint4*)(mP + idx); vp4 = *(const uint4*)(vP + idx); }
    float4 s4 = make_float4(0.f, 0.f, 0.f, 0.f);
    if (mode == 2) s4 = *(const float4*)(S + idx);

    // ---- strip load: 360 uint4 tasks, stored packed ----
    if (interior) {
#pragma unroll
        for (int k = 0; k < 2; ++k) {
            int task = tid + (k << 8);
            if (task < 360) {
                int u = (task * 205) >> 11;      // task/10 exact for task<360
                int v = task - 10 * u;
                *(uint4*)&sP[u][4 * v] =
                    *(const uint4*)(pPrev + base + (size_t)(y0 - 2 + u) * Wd + (x0 - 4 + 4 * v));
            }
        }
    } else {
#pragma unroll
        for (int k = 0; k < 2; ++k) {
            int task = tid + (k << 8);
            if (task < 360) {
                int u = (task * 205) >> 11;
                int v = task - 10 * u;
                int gyy = y0 - 2 + u, gxx = x0 - 4 + 4 * v;
                uint4 w = make_uint4(0u, 0u, 0u, 0u);
                if ((unsigned)gyy < 256u && (unsigned)gxx < 256u)
                    w = *(const uint4*)(pPrev + base + (size_t)gyy * Wd + gxx);
                *(uint4*)&sP[u][4 * v] = w;
            }
        }
    }

    // ---- SSB coef prologue on wave 3 only (overlaps strip load) ----
    if (tid >= 192) {
        int l = tid - 192;
        unsigned long long ax = accPrev[l * 8];
        unsigned long long ay = accPrev[l * 8 + 1];
#pragma unroll
        for (int off = 1; off < 64; off <<= 1) {
            ax += __shfl_xor(ax, off, 64);
            ay += __shfl_xor(ay, off, 64);
        }
        if (l == 0) {
            double axd = (double)ax * (1.0 / SCFP);
            double ayd = (double)ay * (1.0 / SCFP);
            double nxd = sqrt(axd), nyd = sqrt(ayd);
            double pnd = nxd + nyd;
            double uu = pnd * pnd - 0.01;             // V^2
            double sg = (uu > 0.0) ? 1.0 : ((uu < 0.0) ? -1.0 : 0.0);
            sRed[6] = (float)(0.2 * sg * pnd / nxd);
            sRed[7] = (float)(0.2 * sg * pnd / nyd);
        }
    }
    __syncthreads();
    const float coefx = sRed[6];
    const float coefy = sRed[7];

    const __half2 k8 = __float2half2_rn(0.125f);
    const __half2 k4 = __float2half2_rn(0.25f);
    const __half2 h4 = __float2half2_rn(4.0f);
    const __half2 h6 = __float2half2_rn(6.0f);
    const __half2 hn2 = __float2half2_rn(-2.0f);

    float dKx[4], dKy[4], pxa[4], pya[4];

    if (interior) {
        // ---- row pass: 288 tasks (36 rows x 8 groups), composed-kernel halves
        //  A = phi[x-2] - 2 phi[x] + phi[x+2]   (D row)
        //  B = phi[x-2] + 4 phi[x-1] + 6 phi[x] + 4 phi[x+1] + phi[x+2]  (S row)
#pragma unroll
        for (int k = 0; k < 2; ++k) {
            int task = tid + (k << 8);
            if (task < 288) {
                int u = task >> 3, g = task & 7;
                uint4 W0 = *(uint4*)&sP[u][4 * g];
                uint4 W1 = *(uint4*)&sP[u][4 * g + 4];
                uint4 W2 = *(uint4*)&sP[u][4 * g + 8];
                __half2 w[12] = {ash2(W0.x), ash2(W0.y), ash2(W0.z), ash2(W0.w),
                                 ash2(W1.x), ash2(W1.y), ash2(W1.z), ash2(W1.w),
                                 ash2(W2.x), ash2(W2.y), ash2(W2.z), ash2(W2.w)};
                unsigned au[4], bu[4];
#pragma unroll
                for (int jj = 0; jj < 4; ++jj) {
                    __half2 e = __hadd2(w[2 + jj], w[6 + jj]);
                    __half2 A = __hfma2(hn2, w[4 + jj], e);
                    __half2 f = __hadd2(w[3 + jj], w[5 + jj]);
                    __half2 B = __hfma2(h6, w[4 + jj], __hfma2(h4, f, e));
                    au[jj] = asu32(A);
                    bu[jj] = asu32(B);
                }
                *(uint4*)&sA[u][4 * g] = make_uint4(au[0], au[1], au[2], au[3]);
                *(uint4*)&sB[u][4 * g] = make_uint4(bu[0], bu[1], bu[2], bu[3]);
            }
        }
        __syncthreads();

        // ---- column pass: dK_raw = S-col(A) + D-col(B) (scale folded in ckin)
        {
            uint4 pw = *(uint4*)&sP[rr + 2][4 * cgi + 4];
            unsigned pwv[4] = {pw.x, pw.y, pw.z, pw.w};
#pragma unroll
            for (int j = 0; j < 4; ++j) {
                float2 f = __half22float2(ash2(pwv[j]));
                pxa[j] = f.x; pya[j] = f.y;
            }
            const int cb = 4 * cgi;
            uint4 A0 = *(uint4*)&sA[rr][cb];
            uint4 A1 = *(uint4*)&sA[rr + 1][cb];
            uint4 A2 = *(uint4*)&sA[rr + 2][cb];
            uint4 A3 = *(uint4*)&sA[rr + 3][cb];
            uint4 A4 = *(uint4*)&sA[rr + 4][cb];
            uint4 B0 = *(uint4*)&sB[rr][cb];
            uint4 B2 = *(uint4*)&sB[rr + 2][cb];
            uint4 B4 = *(uint4*)&sB[rr + 4][cb];
            unsigned a0[4] = {A0.x, A0.y, A0.z, A0.w};
            unsigned a1[4] = {A1.x, A1.y, A1.z, A1.w};
            unsigned a2v[4] = {A2.x, A2.y, A2.z, A2.w};
            unsigned a3[4] = {A3.x, A3.y, A3.z, A3.w};
            unsigned a4[4] = {A4.x, A4.y, A4.z, A4.w};
            unsigned b0[4] = {B0.x, B0.y, B0.z, B0.w};
            unsigned b2[4] = {B2.x, B2.y, B2.z, B2.w};
            unsigned b4[4] = {B4.x, B4.y, B4.z, B4.w};
#pragma unroll
            for (int jj = 0; jj < 4; ++jj) {
                __half2 g1 = __hadd2(ash2(a0[jj]), ash2(a4[jj]));
                __half2 g2 = __hadd2(ash2(a1[jj]), ash2(a3[jj]));
                __half2 colA = __hfma2(h6, ash2(a2v[jj]), __hfma2(h4, g2, g1));
                __half2 g3 = __hadd2(ash2(b0[jj]), ash2(b4[jj]));
                __half2 colB = __hfma2(hn2, ash2(b2[jj]), g3);
                float2 f = __half22float2(__hadd2(colA, colB));
                dKx[jj] = f.x; dKy[jj] = f.y;
            }
        }
    } else {
        // ---- border: exact two-stage path (c-stage then d-stage) ----
#pragma unroll
        for (int k = 0; k < 2; ++k) {
            int task = tid + (k << 8);
            if (task < 306) {
                int a = (task * 57) >> 9;            // task/9 exact for task<306
                int v = task - 9 * a;
                uint4 T0 = *(uint4*)&sP[a][4 * v];     uint4 T1 = *(uint4*)&sP[a][4 * v + 4];
                uint4 M0 = *(uint4*)&sP[a + 1][4 * v]; uint4 M1 = *(uint4*)&sP[a + 1][4 * v + 4];
                uint4 B0 = *(uint4*)&sP[a + 2][4 * v]; uint4 B1 = *(uint4*)&sP[a + 2][4 * v + 4];
                __half2 wt[6] = {ash2(T0.x), ash2(T0.y), ash2(T0.z), ash2(T0.w), ash2(T1.x), ash2(T1.y)};
                __half2 wm[6] = {ash2(M0.x), ash2(M0.y), ash2(M0.z), ash2(M0.w), ash2(M1.x), ash2(M1.y)};
                __half2 wb[6] = {ash2(B0.x), ash2(B0.y), ash2(B0.z), ash2(B0.w), ash2(B1.x), ash2(B1.y)};
                int gyy = y0 - 1 + a;
                bool rowok = (unsigned)gyy < 256u;
                unsigned c1u[4], c2u[4];
#pragma unroll
                for (int jj = 0; jj < 4; ++jj) {
                    __half2 c1 = __hfma2(k4, __hsub2(wm[jj + 2], wm[jj]),
                                 __hmul2(k8, __hadd2(__hsub2(wt[jj + 2], wt[jj]),
                                                     __hsub2(wb[jj + 2], wb[jj]))));
                    __half2 c2 = __hfma2(k4, __hsub2(wb[jj + 1], wt[jj + 1]),
                                 __hmul2(k8, __hadd2(__hsub2(wb[jj], wt[jj]),
                                                     __hsub2(wb[jj + 2], wt[jj + 2]))));
                    unsigned msk = (rowok && (unsigned)(x0 + 4 * v - 3 + jj) < 256u)
                                   ? 0xFFFFFFFFu : 0u;
                    c1u[jj] = asu32(c1) & msk;
                    c2u[jj] = asu32(c2) & msk;
                }
                *(uint4*)&sA[a][4 * v] = make_uint4(c1u[0], c1u[1], c1u[2], c1u[3]);
                *(uint4*)&sB[a][4 * v] = make_uint4(c2u[0], c2u[1], c2u[2], c2u[3]);
            }
        }
        __syncthreads();
        {
            uint4 pw = *(uint4*)&sP[rr + 2][4 * cgi + 4];
            unsigned pwv[4] = {pw.x, pw.y, pw.z, pw.w};
#pragma unroll
            for (int j = 0; j < 4; ++j) {
                float2 f = __half22float2(ash2(pwv[j]));
                pxa[j] = f.x; pya[j] = f.y;
            }
            const int cb = 4 * cgi;
            uint4 U0a = *(uint4*)&sA[rr][cb];     uint4 U0b = *(uint4*)&sA[rr][cb + 4];
            uint4 U1a = *(uint4*)&sA[rr + 1][cb]; uint4 U1b = *(uint4*)&sA[rr + 1][cb + 4];
            uint4 U2a = *(uint4*)&sA[rr + 2][cb]; uint4 U2b = *(uint4*)&sA[rr + 2][cb + 4];
            uint4 V0a = *(uint4*)&sB[rr][cb];     uint4 V0b = *(uint4*)&sB[rr][cb + 4];
            uint4 V2a = *(uint4*)&sB[rr + 2][cb]; uint4 V2b = *(uint4*)&sB[rr + 2][cb + 4];
            __half2 u0[8] = {ash2(U0a.x), ash2(U0a.y), ash2(U0a.z), ash2(U0a.w),
                             ash2(U0b.x), ash2(U0b.y), ash2(U0b.z), ash2(U0b.w)};
            __half2 u1[8] = {ash2(U1a.x), ash2(U1a.y), ash2(U1a.z), ash2(U1a.w),
                             ash2(U1b.x), ash2(U1b.y), ash2(U1b.z), ash2(U1b.w)};
            __half2 u2[8] = {ash2(U2a.x), ash2(U2a.y), ash2(U2a.z), ash2(U2a.w),
                             ash2(U2b.x), ash2(U2b.y), ash2(U2b.z), ash2(U2b.w)};
            __half2 t0[8] = {ash2(V0a.x), ash2(V0a.y), ash2(V0a.z), ash2(V0a.w),
                             ash2(V0b.x), ash2(V0b.y), ash2(V0b.z), ash2(V0b.w)};
            __half2 t2[8] = {ash2(V2a.x), ash2(V2a.y), ash2(V2a.z), ash2(V2a.w),
                             ash2(V2b.x), ash2(V2b.y), ash2(V2b.z), ash2(V2b.w)};
#pragma unroll
            for (int jj = 0; jj < 4; ++jj) {
                __half2 A = __hadd2(__hadd2(__hsub2(u0[jj + 4], u0[jj + 2]),
                                            __hsub2(u2[jj + 4], u2[jj + 2])),
                                    __hadd2(__hsub2(t2[jj + 2], t0[jj + 2]),
                                            __hsub2(t2[jj + 4], t0[jj + 4])));
                __half2 B = __hadd2(__hsub2(u1[jj + 4], u1[jj + 2]),
                                    __hsub2(t2[jj + 3], t0[jj + 3]));
                __half2 dk = __hfma2(k4, B, __hmul2(k8, A));
                float2 f = __half22float2(dk);
                dKx[jj] = f.x; dKy[jj] = f.y;
            }
        }
    }

    // ---- pointwise grad + Adam (dx,dy,void precomputed; rsqrt update) ----
    unsigned duv[4] = {d4.x, d4.y, d4.z, d4.w};
    unsigned mpv[4] = {mp4.x, mp4.y, mp4.z, mp4.w};
    unsigned vpv[4] = {vp4.x, vp4.y, vp4.z, vp4.w};
    float sa[4] = {s4.x, s4.y, s4.z, s4.w};

    unsigned nmw[4], nvw[4], npk[4];
    float npx[4], npy[4], spv[4];
    float sumx = 0.f, sumy = 0.f;
#pragma unroll
    for (int j = 0; j < 4; ++j) {
        float2 dd = __half22float2(ash2(duv[j]));
        float dx_ = dd.x, dy_ = dd.y;
        float vmc = (duv[j] & 1u) ? C_VOID : 0.f;
        float R = pxa[j] * dx_ + pya[j] * dy_;
        float gx_ = C_COUP * R * dx_ - ckin * dKx[j] + (coefx + vmc) * pxa[j];
        float gy_ = C_COUP * R * dy_ - ckin * dKy[j] + (coefy + vmc) * pya[j];

        float m1 = first ? (0.1f * gx_) : (0.9f * bflo(mpv[j]) + 0.1f * gx_);
        float v1 = first ? (0.001f * gx_ * gx_) : (0.999f * bflo(vpv[j]) + 0.001f * gx_ * gx_);
        npx[j] = fmaf(-a2 * m1, __frsqrt_rn(v1), pxa[j]);
        sumx += npx[j] * npx[j];

        float m2 = first ? (0.1f * gy_) : (0.9f * bfhi(mpv[j]) + 0.1f * gy_);
        float v2 = first ? (0.001f * gy_ * gy_) : (0.999f * bfhi(vpv[j]) + 0.001f * gy_ * gy_);
        npy[j] = fmaf(-a2 * m2, __frsqrt_rn(v2), pya[j]);
        sumy += npy[j] * npy[j];

        nmw[j] = bfpack(m1, m2);
        nvw[j] = bfpack(v1, v2);
        npk[j] = packh2z(npx[j], npy[j]);
        spv[j] = sa[j] + R;
    }
    if (mode != 2) {   // last step: state never read again
        *(uint4*)(mP + idx) = make_uint4(nmw[0], nmw[1], nmw[2], nmw[3]);
        *(uint4*)(vP + idx) = make_uint4(nvw[0], nvw[1], nvw[2], nvw[3]);
        *(uint4*)(pCur + idx) = make_uint4(npk[0], npk[1], npk[2], npk[3]);
    }
    if (mode != 0) {
        *(float4*)(outx + idx) = make_float4(npx[0], npx[1], npx[2], npx[3]);
        *(float4*)(outy + idx) = make_float4(npy[0], npy[1], npy[2], npy[3]);
    }
    if (mode == 2) {
        *(float4*)(sp + idx) = make_float4(spv[0], spv[1], spv[2], spv[3]);
        return;   // acc[50] is never read — skip the reduce+atomic
    }

    block_acc(sumx, sumy, sRed, accCur + (size_t)zsl * 8);
}

// init: pack phi0 -> p0, precompute packed (dx,dy,void) from S, ||phi0||^2
__global__ __launch_bounds__(256)
void k_init(const float* __restrict__ S,
            const float* __restrict__ px0, const float* __restrict__ py0,
            unsigned* __restrict__ p0, unsigned* __restrict__ dxy,
            unsigned long long* __restrict__ acc0)
{
    __shared__ float sRed[8];
    const int tid = threadIdx.x;
    float sx = 0.f, sy = 0.f;
#pragma unroll
    for (int k = 0; k < 2; ++k) {
        size_t idx = (size_t)blockIdx.x * 2048 + (size_t)(k * 1024 + tid * 4);
        float4 x = *(const float4*)(px0 + idx);
        float4 y = *(const float4*)(py0 + idx);
        *(uint4*)(p0 + idx) = make_uint4(packh2(x.x, y.x), packh2(x.y, y.y),
                                         packh2(x.z, y.z), packh2(x.w, y.w));
        sx += x.x * x.x + x.y * x.y + x.z * x.z + x.w * x.w;
        sy += y.x * y.x + y.y * y.y + y.z * y.z + y.w * y.w;

        // dx,dy,void pack
        int col = (int)(idx & 255u);
        int row = (int)((idx >> 8) & 255u);
        float4 s4 = *(const float4*)(S + idx);
        float sa[4] = {s4.x, s4.y, s4.z, s4.w};
        float sE = (col + 4 < 256) ? S[idx + 4] : 0.f;
        float4 sD = (row < 255) ? *(const float4*)(S + idx + 256) : make_float4(0.f, 0.f, 0.f, 0.f);
        float sd[4] = {sD.x, sD.y, sD.z, sD.w};
        unsigned du[4];
#pragma unroll
        for (int j = 0; j < 4; ++j) {
            float dx_ = (j < 3) ? (sa[j + 1] - sa[j]) : ((col + 4 < 256) ? (sE - sa[3]) : 0.f);
            float dy_ = (row < 255) ? (sd[j] - sa[j]) : 0.f;
            unsigned u = packh2(dx_, dy_);
            du[j] = (u & ~1u) | ((sa[j] < 0.05f) ? 1u : 0u);
        }
        *(uint4*)(dxy + idx) = make_uint4(du[0], du[1], du[2], du[3]);
    }
    block_acc(sx, sy, sRed, acc0 + (size_t)(blockIdx.x & (NSLOT - 1)) * 8);
}

extern "C" void kernel_launch(void* const* d_in, const int* in_sizes, int n_in,
                              void* d_out, int out_size, void* d_ws, size_t ws_size,
                              hipStream_t stream) {
    (void)in_sizes; (void)n_in; (void)out_size; (void)ws_size;
    const float* S   = (const float*)d_in[0];
    const float* px0 = (const float*)d_in[1];
    const float* py0 = (const float*)d_in[2];
    float* out = (float*)d_out;

    float* sp     = out;                      // slot 0: Sp
    float* outA_x = out + (size_t)NTOT;       // slot 1: phi_x post
    float* outA_y = out + 2 * (size_t)NTOT;   // slot 2: phi_y post
    float* outB_x = out + 3 * (size_t)NTOT;   // slot 3: phi_x pre
    float* outB_y = out + 4 * (size_t)NTOT;   // slot 4: phi_y pre

    unsigned* ws = (unsigned*)d_ws;
    unsigned* p0 = ws;                        // packed (fp16 phix, fp16 phiy), 16 MB
    unsigned* p1 = p0 + (size_t)NTOT;         // ping-pong partner, 16 MB
    unsigned* mP = p1 + (size_t)NTOT;         // packed (bf16 mx, bf16 my), 16 MB
    unsigned* vP = mP + (size_t)NTOT;         // packed (bf16 vx, bf16 vy), 16 MB
    unsigned* dxy = vP + (size_t)NTOT;        // packed (fp16 dx, fp16 dy | void), 16 MB
    unsigned long long* acc = (unsigned long long*)(dxy + (size_t)NTOT);  // [NACC][NSLOT][8]

    hipError_t e = hipMemsetAsync(acc, 0, (size_t)NACC * NSLOT * 8 * sizeof(unsigned long long), stream);
    (void)e;

    k_init<<<2048, 256, 0, stream>>>(S, px0, py0, p0, dxy, acc);

    for (int t = 1; t <= 50; ++t) {
        double bc1 = 1.0 - pow(0.9, (double)t);
        double bc2 = 1.0 - pow(0.999, (double)t);
        float a2 = (float)(0.05 / bc1 * sqrt(bc2));   // LR/bc1 * sqrt(bc2)
        bool odd = (t & 1) != 0;
        const unsigned* pPrev = odd ? p0 : p1;
        unsigned* pCur = odd ? p1 : p0;
        int mode = (t == 49) ? 1 : ((t == 50) ? 2 : 0);
        float* ox = (t == 50) ? outA_x : outB_x;   // mode1 -> pre slots, mode2 -> post
        float* oy = (t == 50) ? outA_y : outB_y;
        k_step<<<4096, 256, 0, stream>>>(S, dxy, pPrev, pCur, mP, vP,
                                         acc + (size_t)(t - 1) * NSLOT * 8,
                                         acc + (size_t)t * NSLOT * 8,
                                         a2, mode, (t == 1) ? 1 : 0,
                                         ox, oy, sp);
    }
}